// Round 8
// baseline (192.341 us; speedup 1.0000x reference)
//
#include <hip/hip_runtime.h>
#include <stdint.h>
#include <stddef.h>

// GA3 conv2d == one dense 3x3 conv with sign-permuted weights:
//   out[b, c*8+m, h, w] = bias_eff[c*8+m]
//     + sum_{cin,k,kh,kw} s(m,k) * W[j(m,k),c,cin,kh,kw] * x[b, cin*8+k, h+kh-1, w+kw-1]
// bf16 MFMA implicit GEMM over 9 taps (K=128 each).
// R5: conv = R1 body + __launch_bounds__(256,3): LDS already caps at 3 blocks/CU,
// so raise the VGPR cap 128->~168 and let the unrolled loop software-pipeline the
// B-loads (VGPR=128 was the pipelining blocker; MfmaUtil 23-30%).
// prep merged into xpose (independent work, one kernel, one less launch gap).

typedef __attribute__((ext_vector_type(8))) short short8;   // 8 x bf16 (4 VGPRs)
typedef __attribute__((ext_vector_type(4))) float f32x4;    // MFMA accumulator

// j(m,k) and s(m,k): unique j with S[m,j,k]!=0, transcribed from _TERMS.
__device__ __constant__ int c_J[64] = {
  0,1,2,3,4,5,6,7,
  1,0,4,6,2,7,3,5,
  2,4,0,5,1,3,7,6,
  3,6,5,0,7,2,1,4,
  4,2,1,7,0,6,5,3,
  5,7,3,2,6,0,4,1,
  6,3,7,1,5,4,0,2,
  7,5,6,4,3,1,2,0
};
__device__ __constant__ float c_Sg[64] = {
  1,1,1,1,-1,-1,-1,-1,
  1,1,-1,-1,1,-1,1,-1,
  1,1,1,-1,-1,1,1,1,
  1,1,1,1,-1,-1,-1,-1,
  1,1,-1,1,1,1,-1,1,
  1,1,1,-1,-1,1,1,1,
  1,1,-1,-1,1,-1,1,-1,
  1,1,-1,1,1,1,-1,1
};

__device__ inline unsigned short f2bf(float f) {  // RNE float->bf16
  unsigned int u = __float_as_uint(f);
  u += 0x7FFFu + ((u >> 16) & 1u);
  return (unsigned short)(u >> 16);
}

// ---------------- Merged prep: blocks [0,1024) transpose x -> xt (incl. border zero);
// blocks [1024,1600) build vt + beff. Independent work, concurrent on different CUs.
//
// xpose part: x [8][128][128][128] f32 NCHW -> xt [8][130][130][128] bf16 NHWC (padded).
// One block per (h, b): full 128-w row, all 128 ic. float4 reads (512B/32-lane group),
// LDS [ic][stride 129] (odd stride: both phases 2-way = free), uint2 writes (512B/wave).
// Border zeroing folded in: col 0/129 every block; rows 0/129 in h==0/127 blocks.
//
// vt layout: vt[t][ks][ocb][lane][8] bf16 — per-wave B-fragment is one coalesced 1KB
// load: oc = ocb*16 + (lane&15), ic = ks*32 + (lane>>4)*8 + e.  Also bias_eff[128] f32.
__global__ __launch_bounds__(256) void prep_kernel(const float* __restrict__ x,
                                                   unsigned short* __restrict__ xt,
                                                   const float* __restrict__ W,
                                                   const float* __restrict__ bias,
                                                   unsigned short* __restrict__ vt,
                                                   float* __restrict__ beff) {
  __shared__ unsigned short t[128 * 129];   // 33,024 B (xpose part only)
  const int bid = blockIdx.x;
  const int tid = threadIdx.x;
  if (bid < 1024) {
    const int h = bid & 127;
    const int b = bid >> 7;
    // Phase 1: global float4 -> bf16 -> LDS [ic][w]
    #pragma unroll
    for (int i = 0; i < 16; ++i) {
      int idx = tid + i * 256;        // 0..4095 = 128 ic * 32 w-quads
      int ic = idx >> 5, wq = idx & 31;
      const float4 v = *(const float4*)(x + ((size_t)(b * 128 + ic) * 128 + h) * 128 + 4 * wq);
      unsigned short* d = t + ic * 129 + 4 * wq;
      d[0] = f2bf(v.x); d[1] = f2bf(v.y); d[2] = f2bf(v.z); d[3] = f2bf(v.w);
    }
    // Border: cols 0 and 129 of this row (h+1)
    if (tid < 128) {
      int c = tid >> 6, u = tid & 63;
      *(unsigned int*)(xt + ((size_t)(b * 130 + h + 1) * 130 + c * 129) * 128 + 2 * u) = 0u;
    }
    // Border: rows 0 / 129 (only the h==0 / h==127 blocks)
    if (h == 0 || h == 127) {
      int row = (h == 0) ? 0 : 129;
      for (int i = 0; i < 33; ++i) {
        int idx = tid + i * 256;      // 130 px * 64 uints = 8320
        if (idx < 8320) {
          int w = idx >> 6, u = idx & 63;
          *(unsigned int*)(xt + ((size_t)(b * 130 + row) * 130 + w) * 128 + 2 * u) = 0u;
        }
      }
    }
    __syncthreads();
    // Phase 2: LDS -> global, ic-contiguous uint2 (4 ic per lane per iter)
    #pragma unroll
    for (int i = 0; i < 16; ++i) {
      int idx = tid + i * 256;        // 0..4095 = 128 w * 32 ic-quads
      int w = idx >> 5, p4 = idx & 31;
      unsigned int s0 = t[(4 * p4 + 0) * 129 + w];
      unsigned int s1 = t[(4 * p4 + 1) * 129 + w];
      unsigned int s2 = t[(4 * p4 + 2) * 129 + w];
      unsigned int s3 = t[(4 * p4 + 3) * 129 + w];
      uint2 o; o.x = s0 | (s1 << 16); o.y = s2 | (s3 << 16);
      *(uint2*)(xt + ((size_t)(b * 130 + h + 1) * 130 + (w + 1)) * 128 + 4 * p4) = o;
    }
  } else {
    int gid = (bid - 1024) * 256 + tid;   // 9*128*128 = 147456 threads exactly
    int t9  = gid >> 14;
    int rem = gid & 16383;
    int oc  = rem >> 7;
    int ic  = rem & 127;
    int m = oc & 7, cout = oc >> 3;
    int k = ic & 7, cin = ic >> 3;
    int j = c_J[m * 8 + k];
    float s = c_Sg[m * 8 + k];
    float val = s * W[((j * 16 + cout) * 16 + cin) * 9 + t9];
    int ks = ic >> 5, quad = (ic >> 3) & 3, e = ic & 7;
    int ocb = oc >> 4, l15 = oc & 15;
    vt[(size_t)((t9 * 4 + ks) * 8 + ocb) * 512 + (quad * 16 + l15) * 8 + e] = f2bf(val);
    if (gid < 128) {
      int m2 = gid & 7, cout2 = gid >> 3;
      float acc = 0.f;
      #pragma unroll
      for (int kk = 0; kk < 8; ++kk)
        acc += c_Sg[m2 * 8 + kk] * bias[c_J[m2 * 8 + kk] * 16 + cout2];
      beff[gid] = acc;
    }
  }
}

// ---------------- Main: tap-decomposed implicit GEMM, bf16 MFMA 16x16x32 ----------------
// (R1 body, measured 49-61us; only change: __launch_bounds__(256,3) raises VGPR cap
// to ~168 so the fully-unrolled loop can keep ~3 iterations of B-loads in flight.
// LDS 45KiB already caps occupancy at 3 blocks/CU, so no occupancy is lost.)
// Block: 256 thr = 4 waves. Tile: 8 rows x 16 cols of output pixels x all 128 oc.
// lds_x XOR-swizzled: 16B chunk c stored at c ^ ((c>>4)&7)  (row = c>>4 = hh*18+ww).
// B-fragments come straight from global vt (L2-resident, coalesced 1KB/wave load).
// Exactly ONE barrier per block.
__global__ __launch_bounds__(256, 3) void conv_kernel(const unsigned short* __restrict__ xt,
                                                      const unsigned short* __restrict__ vt,
                                                      const float* __restrict__ beff,
                                                      float* __restrict__ out) {
  __shared__ __align__(16) unsigned short lds_x[10 * 18 * 128]; // halo [hh][ww][ic], 45 KiB
  const int tid  = threadIdx.x;
  const int bx   = blockIdx.x;    // 0..7   w tile (16)
  const int by   = blockIdx.y;    // 0..15  h tile (8)
  const int b    = blockIdx.z;    // 0..7
  const int lane = tid & 63;
  const int wave = tid >> 6;
  const int wm   = wave >> 1;     // 0..1
  const int wn   = wave & 1;      // 0..1
  const int l15  = lane & 15;
  const int quad = lane >> 4;

  // Stage x halo tile (rows by*8..+9, cols bx*16..+17, 128 ic) = 2880 x 16B chunks,
  // swizzled on the write side.
  {
    const unsigned short* xb = xt + ((size_t)(b * 130 + by * 8) * 130 + bx * 16) * 128;
    #pragma unroll
    for (int i = 0; i < 11; ++i) {
      int c  = tid + i * 256;
      int hh = c / 288;            // 288 chunks per halo row (18*128*2B/16B)
      int r  = c - hh * 288;
      uint4 v = *((const uint4*)(xb + (size_t)hh * (130 * 128)) + r);
      ((uint4*)lds_x)[c ^ ((c >> 4) & 7)] = v;
    }
    if (tid < 64) {                // tail: chunks 2816..2879
      int c  = tid + 2816;
      int hh = c / 288;
      int r  = c - hh * 288;
      uint4 v = *((const uint4*)(xb + (size_t)hh * (130 * 128)) + r);
      ((uint4*)lds_x)[c ^ ((c >> 4) & 7)] = v;
    }
  }
  __syncthreads();                 // the only barrier

  f32x4 acc[4][4];
  #pragma unroll
  for (int mi = 0; mi < 4; ++mi)
    #pragma unroll
    for (int ni = 0; ni < 4; ++ni)
      acc[mi][ni] = f32x4{0.f, 0.f, 0.f, 0.f};

  const unsigned short* vtw = vt + (size_t)(wn * 4) * 512 + (size_t)lane * 8;

  #pragma unroll
  for (int t = 0; t < 9; ++t) {
    const int dh = t / 3, dw = t % 3;
    int rowb[4];
    #pragma unroll
    for (int mi = 0; mi < 4; ++mi)
      rowb[mi] = (wm * 4 + mi + dh) * 18 + l15 + dw;   // per-lane LDS row
    #pragma unroll
    for (int ks = 0; ks < 4; ++ks) {                   // K = 128 = 4 x 32
      short8 bb[4];
      #pragma unroll
      for (int ni = 0; ni < 4; ++ni)                   // coalesced 1KB wave load, L1/L2 hit
        bb[ni] = *(const short8*)(vtw + (size_t)((t * 4 + ks) * 8 + ni) * 512);
      short8 a[4];
      #pragma unroll
      for (int mi = 0; mi < 4; ++mi) {
        int row = rowb[mi];
        int off = row * 256 + ((ks * 64 + quad * 16) ^ ((row & 7) << 4));  // swizzled read
        a[mi] = *(const short8*)((const char*)lds_x + off);
      }
      #pragma unroll
      for (int mi = 0; mi < 4; ++mi)
        #pragma unroll
        for (int ni = 0; ni < 4; ++ni)
          acc[mi][ni] = __builtin_amdgcn_mfma_f32_16x16x32_bf16(a[mi], bb[ni], acc[mi][ni], 0, 0, 0);
    }
  }

  // Epilogue: D row = quad*4+reg (pixel w offset), col = l15 (oc). float4 stores, w-contiguous.
  const int h0 = by * 8, w0 = bx * 16;
  #pragma unroll
  for (int ni = 0; ni < 4; ++ni) {
    int oc = (wn * 4 + ni) * 16 + l15;
    float bv = beff[oc];
    #pragma unroll
    for (int mi = 0; mi < 4; ++mi) {
      int h = h0 + wm * 4 + mi;
      int w = w0 + quad * 4;
      f32x4 v = acc[mi][ni];
      v[0] += bv; v[1] += bv; v[2] += bv; v[3] += bv;
      *(f32x4*)(out + ((size_t)(b * 128 + oc) * 128 + h) * 128 + w) = v;
    }
  }
}

extern "C" void kernel_launch(void* const* d_in, const int* in_sizes, int n_in,
                              void* d_out, int out_size, void* d_ws, size_t ws_size,
                              hipStream_t stream) {
  (void)in_sizes; (void)n_in; (void)out_size; (void)ws_size;
  const float* x    = (const float*)d_in[0];   // [8][128][128][128]
  const float* W    = (const float*)d_in[1];   // [8][16][16][3][3]
  const float* bias = (const float*)d_in[2];   // [8][16]
  float* out = (float*)d_out;                  // [8][128][128][128]

  const size_t XT_BYTES = (size_t)8 * 130 * 130 * 128 * 2;   // 34,611,200
  const size_t VT_BYTES = (size_t)9 * 4 * 8 * 512 * 2;       //    294,912
  unsigned short* xt = (unsigned short*)d_ws;
  unsigned short* vt = (unsigned short*)((char*)d_ws + XT_BYTES);
  float* beff = (float*)((char*)d_ws + XT_BYTES + VT_BYTES);

  prep_kernel<<<dim3(1600), 256, 0, stream>>>(x, xt, W, bias, vt, beff); // xpose+vt+beff+border
  conv_kernel<<<dim3(8, 16, 8), 256, 0, stream>>>(xt, vt, beff, out);
}

// Round 9
// 154.077 us; speedup vs baseline: 1.2483x; 1.2483x over previous
//
#include <hip/hip_runtime.h>
#include <stdint.h>
#include <stddef.h>

// GA3 conv2d == one dense 3x3 conv with sign-permuted weights:
//   out[b, c*8+m, h, w] = bias_eff[c*8+m]
//     + sum_{cin,k,kh,kw} s(m,k) * W[j(m,k),c,cin,kh,kw] * x[b, cin*8+k, h+kh-1, w+kw-1]
// bf16 MFMA implicit GEMM over 9 taps (K=128 each).
// R6: B staged per-tap into LDS via global_load_lds (async DMA, zero VGPR cost) --
// removes the per-ks L2 B-load latency that VGPR=128 couldn't pipeline.
// launch_bounds hints removed (R3/R5: any waves-per-EU hint makes the allocator
// spill; VGPR must stay at the default cap). LDS 45+32=78.8KB -> 2 blocks/CU.
// xpose/prep restored to the R4 separate-kernel form (measured good).

typedef __attribute__((ext_vector_type(8))) short short8;   // 8 x bf16 (4 VGPRs)
typedef __attribute__((ext_vector_type(4))) float f32x4;    // MFMA accumulator

#define GLD_LDS16(gsrc, ldst) __builtin_amdgcn_global_load_lds( \
    (const __attribute__((address_space(1))) void*)(gsrc),      \
    (__attribute__((address_space(3))) void*)(ldst), 16, 0, 0)

// j(m,k) and s(m,k): unique j with S[m,j,k]!=0, transcribed from _TERMS.
__device__ __constant__ int c_J[64] = {
  0,1,2,3,4,5,6,7,
  1,0,4,6,2,7,3,5,
  2,4,0,5,1,3,7,6,
  3,6,5,0,7,2,1,4,
  4,2,1,7,0,6,5,3,
  5,7,3,2,6,0,4,1,
  6,3,7,1,5,4,0,2,
  7,5,6,4,3,1,2,0
};
__device__ __constant__ float c_Sg[64] = {
  1,1,1,1,-1,-1,-1,-1,
  1,1,-1,-1,1,-1,1,-1,
  1,1,1,-1,-1,1,1,1,
  1,1,1,1,-1,-1,-1,-1,
  1,1,-1,1,1,1,-1,1,
  1,1,1,-1,-1,1,1,1,
  1,1,-1,-1,1,-1,1,-1,
  1,1,-1,1,1,1,-1,1
};

__device__ inline unsigned short f2bf(float f) {  // RNE float->bf16
  unsigned int u = __float_as_uint(f);
  u += 0x7FFFu + ((u >> 16) & 1u);
  return (unsigned short)(u >> 16);
}

// ---------------- Prep A: x [8][128][128][128] f32 NCHW -> xt [8][130][130][128] bf16 NHWC
// (padded). One block per (h, b): full 128-w row, all 128 ic. float4 reads,
// LDS [ic][stride 129] (odd stride: both phases 2-way = free), uint2 writes.
// Border zeroing folded in: col 0/129 every block; rows 0/129 in h==0/127 blocks.
__global__ __launch_bounds__(256) void xpose_kernel(const float* __restrict__ x,
                                                    unsigned short* __restrict__ xt) {
  __shared__ unsigned short t[128 * 129];   // 33,024 B
  const int h   = blockIdx.x;       // 0..127
  const int b   = blockIdx.y;       // 0..7
  const int tid = threadIdx.x;
  // Phase 1: global float4 -> bf16 -> LDS [ic][w]
  #pragma unroll
  for (int i = 0; i < 16; ++i) {
    int idx = tid + i * 256;        // 0..4095 = 128 ic * 32 w-quads
    int ic = idx >> 5, wq = idx & 31;
    const float4 v = *(const float4*)(x + ((size_t)(b * 128 + ic) * 128 + h) * 128 + 4 * wq);
    unsigned short* d = t + ic * 129 + 4 * wq;
    d[0] = f2bf(v.x); d[1] = f2bf(v.y); d[2] = f2bf(v.z); d[3] = f2bf(v.w);
  }
  // Border: cols 0 and 129 of this row (h+1)
  if (tid < 128) {
    int c = tid >> 6, u = tid & 63;
    *(unsigned int*)(xt + ((size_t)(b * 130 + h + 1) * 130 + c * 129) * 128 + 2 * u) = 0u;
  }
  // Border: rows 0 / 129 (only the h==0 / h==127 blocks)
  if (h == 0 || h == 127) {
    int row = (h == 0) ? 0 : 129;
    for (int i = 0; i < 33; ++i) {
      int idx = tid + i * 256;      // 130 px * 64 uints = 8320
      if (idx < 8320) {
        int w = idx >> 6, u = idx & 63;
        *(unsigned int*)(xt + ((size_t)(b * 130 + row) * 130 + w) * 128 + 2 * u) = 0u;
      }
    }
  }
  __syncthreads();
  // Phase 2: LDS -> global, ic-contiguous uint2 (4 ic per lane per iter)
  #pragma unroll
  for (int i = 0; i < 16; ++i) {
    int idx = tid + i * 256;        // 0..4095 = 128 w * 32 ic-quads
    int w = idx >> 5, p4 = idx & 31;
    unsigned int s0 = t[(4 * p4 + 0) * 129 + w];
    unsigned int s1 = t[(4 * p4 + 1) * 129 + w];
    unsigned int s2 = t[(4 * p4 + 2) * 129 + w];
    unsigned int s3 = t[(4 * p4 + 3) * 129 + w];
    uint2 o; o.x = s0 | (s1 << 16); o.y = s2 | (s3 << 16);
    *(uint2*)(xt + ((size_t)(b * 130 + h + 1) * 130 + (w + 1)) * 128 + 4 * p4) = o;
  }
}

// ---------------- Prep B: vt[t][ks][ocb][lane][8] bf16 — tap t's 32KB block is a flat
// [ks][ocb][512-short] region (copied whole into LDS by conv): oc = ocb*16 + (lane&15),
// ic = ks*32 + (lane>>4)*8 + e.  Also bias_eff[128] f32.
__global__ __launch_bounds__(256) void prep_kernel(const float* __restrict__ W,
                                                   const float* __restrict__ bias,
                                                   unsigned short* __restrict__ vt,
                                                   float* __restrict__ beff) {
  int gid = blockIdx.x * 256 + threadIdx.x;   // 9*128*128 = 147456 threads exactly
  int t   = gid >> 14;
  int rem = gid & 16383;
  int oc  = rem >> 7;
  int ic  = rem & 127;
  int m = oc & 7, cout = oc >> 3;
  int k = ic & 7, cin = ic >> 3;
  int j = c_J[m * 8 + k];
  float s = c_Sg[m * 8 + k];
  float val = s * W[((j * 16 + cout) * 16 + cin) * 9 + t];
  int ks = ic >> 5, quad = (ic >> 3) & 3, e = ic & 7;
  int ocb = oc >> 4, l15 = oc & 15;
  vt[(size_t)((t * 4 + ks) * 8 + ocb) * 512 + (quad * 16 + l15) * 8 + e] = f2bf(val);
  if (gid < 128) {
    int m2 = gid & 7, cout2 = gid >> 3;
    float acc = 0.f;
    #pragma unroll
    for (int kk = 0; kk < 8; ++kk)
      acc += c_Sg[m2 * 8 + kk] * bias[c_J[m2 * 8 + kk] * 16 + cout2];
    beff[gid] = acc;
  }
}

// ---------------- Main: tap-decomposed implicit GEMM, bf16 MFMA 16x16x32 ----------------
// Block: 256 thr = 4 waves. Tile: 8 rows x 16 cols of output pixels x all 128 oc.
// lds_x XOR-swizzled: 16B chunk c stored at c ^ ((c>>4)&7)  (row = c>>4 = hh*18+ww).
// lds_w: current tap's 32KB of vt, filled by global_load_lds (async, no VGPRs);
// per tap: barrier -> 8x global_load_lds -> vmcnt(0) -> barrier -> 4ks x 16 MFMA.
// Tap-0 B loads fly under the lds_x staging. LDS 78.8KB -> 2 blocks/CU; the
// co-resident block computes during this block's stage drain.
__global__ __launch_bounds__(256) void conv_kernel(const unsigned short* __restrict__ xt,
                                                   const unsigned short* __restrict__ vt,
                                                   const float* __restrict__ beff,
                                                   float* __restrict__ out) {
  __shared__ __align__(16) unsigned short lds_x[10 * 18 * 128]; // halo [hh][ww][ic], 45 KiB
  __shared__ __align__(16) unsigned short lds_w[128 * 128];     // one tap of B, 32 KiB
  const int tid  = threadIdx.x;
  const int bx   = blockIdx.x;    // 0..7   w tile (16)
  const int by   = blockIdx.y;    // 0..15  h tile (8)
  const int b    = blockIdx.z;    // 0..7
  const int lane = tid & 63;
  const int wave = tid >> 6;
  const int wm   = wave >> 1;     // 0..1
  const int wn   = wave & 1;      // 0..1
  const int l15  = lane & 15;
  const int quad = lane >> 4;

  // Issue tap-0 B loads first: async direct-to-LDS, they complete under x staging.
  #pragma unroll
  for (int i = 0; i < 8; ++i) {
    int c = (tid + i * 256) * 16;   // byte offset; wave-uniform base + lane*16
    GLD_LDS16((const char*)vt + c, (char*)lds_w + c);
  }

  // Stage x halo tile (rows by*8..+9, cols bx*16..+17, 128 ic) = 2880 x 16B chunks,
  // swizzled on the write side.
  {
    const unsigned short* xb = xt + ((size_t)(b * 130 + by * 8) * 130 + bx * 16) * 128;
    #pragma unroll
    for (int i = 0; i < 11; ++i) {
      int c  = tid + i * 256;
      int hh = c / 288;            // 288 chunks per halo row (18*128*2B/16B)
      int r  = c - hh * 288;
      uint4 v = *((const uint4*)(xb + (size_t)hh * (130 * 128)) + r);
      ((uint4*)lds_x)[c ^ ((c >> 4) & 7)] = v;
    }
    if (tid < 64) {                // tail: chunks 2816..2879
      int c  = tid + 2816;
      int hh = c / 288;
      int r  = c - hh * 288;
      uint4 v = *((const uint4*)(xb + (size_t)hh * (130 * 128)) + r);
      ((uint4*)lds_x)[c ^ ((c >> 4) & 7)] = v;
    }
  }
  __syncthreads();                 // drains vmcnt+lgkmcnt: x tile AND tap-0 B ready

  f32x4 acc[4][4];
  #pragma unroll
  for (int mi = 0; mi < 4; ++mi)
    #pragma unroll
    for (int ni = 0; ni < 4; ++ni)
      acc[mi][ni] = f32x4{0.f, 0.f, 0.f, 0.f};

  #pragma unroll
  for (int t = 0; t < 9; ++t) {
    const int dh = t / 3, dw = t % 3;
    int rowb[4];
    #pragma unroll
    for (int mi = 0; mi < 4; ++mi)
      rowb[mi] = (wm * 4 + mi + dh) * 18 + l15 + dw;   // per-lane LDS row
    #pragma unroll
    for (int ks = 0; ks < 4; ++ks) {                   // K = 128 = 4 x 32
      short8 bb[4];
      #pragma unroll
      for (int ni = 0; ni < 4; ++ni)                   // contiguous 1KB/wave, conflict-free
        bb[ni] = *(const short8*)(lds_w + (ks * 8 + wn * 4 + ni) * 512 + lane * 8);
      short8 a[4];
      #pragma unroll
      for (int mi = 0; mi < 4; ++mi) {
        int row = rowb[mi];
        int off = row * 256 + ((ks * 64 + quad * 16) ^ ((row & 7) << 4));  // swizzled read
        a[mi] = *(const short8*)((const char*)lds_x + off);
      }
      #pragma unroll
      for (int mi = 0; mi < 4; ++mi)
        #pragma unroll
        for (int ni = 0; ni < 4; ++ni)
          acc[mi][ni] = __builtin_amdgcn_mfma_f32_16x16x32_bf16(a[mi], bb[ni], acc[mi][ni], 0, 0, 0);
    }
    if (t < 8) {
      __syncthreads();             // all waves done reading lds_w for tap t
      const char* src = (const char*)vt + (size_t)(t + 1) * 32768;
      #pragma unroll
      for (int i = 0; i < 8; ++i) {
        int c = (tid + i * 256) * 16;
        GLD_LDS16(src + c, (char*)lds_w + c);
      }
      asm volatile("s_waitcnt vmcnt(0)" ::: "memory");
      __syncthreads();             // tap t+1 B ready
    }
  }

  // Epilogue: D row = quad*4+reg (pixel w offset), col = l15 (oc). float4 stores, w-contiguous.
  const int h0 = by * 8, w0 = bx * 16;
  #pragma unroll
  for (int ni = 0; ni < 4; ++ni) {
    int oc = (wn * 4 + ni) * 16 + l15;
    float bv = beff[oc];
    #pragma unroll
    for (int mi = 0; mi < 4; ++mi) {
      int h = h0 + wm * 4 + mi;
      int w = w0 + quad * 4;
      f32x4 v = acc[mi][ni];
      v[0] += bv; v[1] += bv; v[2] += bv; v[3] += bv;
      *(f32x4*)(out + ((size_t)(b * 128 + oc) * 128 + h) * 128 + w) = v;
    }
  }
}

extern "C" void kernel_launch(void* const* d_in, const int* in_sizes, int n_in,
                              void* d_out, int out_size, void* d_ws, size_t ws_size,
                              hipStream_t stream) {
  (void)in_sizes; (void)n_in; (void)out_size; (void)ws_size;
  const float* x    = (const float*)d_in[0];   // [8][128][128][128]
  const float* W    = (const float*)d_in[1];   // [8][16][16][3][3]
  const float* bias = (const float*)d_in[2];   // [8][16]
  float* out = (float*)d_out;                  // [8][128][128][128]

  const size_t XT_BYTES = (size_t)8 * 130 * 130 * 128 * 2;   // 34,611,200
  const size_t VT_BYTES = (size_t)9 * 4 * 8 * 512 * 2;       //    294,912
  unsigned short* xt = (unsigned short*)d_ws;
  unsigned short* vt = (unsigned short*)((char*)d_ws + XT_BYTES);
  float* beff = (float*)((char*)d_ws + XT_BYTES + VT_BYTES);

  prep_kernel<<<dim3(576), 256, 0, stream>>>(W, bias, vt, beff);       // vt + beff
  xpose_kernel<<<dim3(128, 8), 256, 0, stream>>>(x, xt);               // incl. border zero
  conv_kernel<<<dim3(8, 16, 8), 256, 0, stream>>>(xt, vt, beff, out);
}